// Round 7
// baseline (137.613 us; speedup 1.0000x reference)
//
#include <hip/hip_runtime.h>
#include <hip/hip_bf16.h>

// Problem constants (from reference): b=2,h=8 -> BH=16; t=s=384; d=64.
#define BH 16
#define NT 384
#define NS 384
#define DD 64

static constexpr float TWO_LOG2E = 2.8853900817779268f; // 2*log2(e)
static constexpr float LOG2E     = 1.4426950408889634f;

// Static scratch: Ea = exp(2*qp), Eb = exp(2*kp). 2 x 1.5 MB, 16B aligned.
__device__ float4 g_Ea4[(size_t)BH * NT * DD / 4];
__device__ float4 g_Eb4[(size_t)BH * NS * DD / 4];

// ---------------------------------------------------------------------------
// K1: proj + exp. Block owns 32 rows of one tensor (q or k). x-tile staged in
// LDS; W row per lane in VGPRs; x read back as uniform LDS b128 broadcasts.
// ---------------------------------------------------------------------------
__global__ __launch_bounds__(256) void k1_proj(
    const float* __restrict__ q, const float* __restrict__ k,
    const float* __restrict__ Wq, const float* __restrict__ Wk)
{
    __shared__ float xt[32 * 64]; // 8KB
    const int bid    = blockIdx.x;       // [0, 384)
    const int tensor = bid / 192;        // 0=q, 1=k
    const int tile   = bid % 192;        // 32-row tiles over 6144 rows
    const int tid  = threadIdx.x;
    const int lane = tid & 63;
    const int w    = tid >> 6;

    const float* __restrict__ X = tensor ? k  : q;
    const float* __restrict__ W = tensor ? Wk : Wq;
    float* __restrict__ E = tensor ? (float*)g_Eb4 : (float*)g_Ea4;

    const size_t base = (size_t)tile * 32;

    {
        const float4* __restrict__ src =
            reinterpret_cast<const float4*>(X + base * 64);
        float4* dst = reinterpret_cast<float4*>(xt);
#pragma unroll
        for (int i = 0; i < 2; ++i) dst[tid + i * 256] = src[tid + i * 256];
    }

    float wr[64];
    {
        const float* wrow = W + lane * 64;
#pragma unroll
        for (int i = 0; i < 64; i += 4) {
            float4 v = *reinterpret_cast<const float4*>(wrow + i);
            wr[i] = v.x; wr[i + 1] = v.y; wr[i + 2] = v.z; wr[i + 3] = v.w;
        }
    }
    __syncthreads();

#pragma unroll
    for (int r8 = 0; r8 < 8; ++r8) {
        const int r = w * 8 + r8;
        float a0 = 0.f, a1 = 0.f, a2 = 0.f, a3 = 0.f;
#pragma unroll
        for (int d4 = 0; d4 < 16; ++d4) {
            const float4 xv = *reinterpret_cast<const float4*>(&xt[r * 64 + d4 * 4]);
            a0 = fmaf(xv.x, wr[d4 * 4 + 0], a0);
            a1 = fmaf(xv.y, wr[d4 * 4 + 1], a1);
            a2 = fmaf(xv.z, wr[d4 * 4 + 2], a2);
            a3 = fmaf(xv.w, wr[d4 * 4 + 3], a3);
        }
        const float dot = (a0 + a1) + (a2 + a3);
        E[(base + r) * 64 + lane] = __builtin_amdgcn_exp2f(TWO_LOG2E * dot);
    }
}

// ---------------------------------------------------------------------------
// K2 fused v2: scores + softmax + PV for one (bh, 12-t-row) tile per block.
// 384 threads = 6 waves; wave wv owns s-chunk wv (lane<->s within chunk).
// Phase A (no LDS): eb[64] in VGPRs hoisted from global (L2-hot); Ea row and
// v_w are wave-uniform global derefs (compiler scalarizes -> SMEM pipe);
// inner loop is pure fma+rcp+fma. Scores p[12] live in registers.
// Softmax (no max pass; scores bounded by |C0|+2*sum|vw| < 24): exp2 in regs,
// per-row 6-step butterfly for chunk sums, tiny LDS combine, scale in regs,
// single write of P to LDS + global attn.
// PV: V chunk staged [64][68]; lane = (g = s-subgroup, dq = d-quad); V read as
// b128 (each 16-lane group reads a contiguous 256B row slice = conflict-free),
// P read as 4-way-broadcast b32; wave handles rows {2wv, 2wv+1}; final
// shfl_xor(16,32) reduce across subgroups; lanes g==0 write out as float4.
// Grid 512 (16 bh x 32 tiles) = exactly 2 blocks/CU, 12 waves/CU.
// ---------------------------------------------------------------------------
__global__ __launch_bounds__(384, 3) void k2_fused(
    const float* __restrict__ v_w, const float* __restrict__ V,
    float* __restrict__ out, float* __restrict__ attn)
{
    __shared__ float Pl[12 * 388];   // 18.6KB normalized attention tile
    __shared__ float Vt[64 * 68];    // 17.4KB V chunk
    __shared__ float ssum[12 * 8];   // per-row per-wave chunk sums

    const int bid  = blockIdx.x;     // [0, 512)
    const int bh   = bid >> 5;
    const int t0   = (bid & 31) * 12;
    const int tid  = threadIdx.x;
    const int lane = tid & 63;
    const int wv   = __builtin_amdgcn_readfirstlane(tid >> 6); // 0..5

    // C0 = sum(v_w) — uniform scalar chain
    float C0 = 0.f;
#pragma unroll
    for (int i = 0; i < 64; ++i) C0 += v_w[i];

    // eb[64]: this lane's Eb row (s = wv*64 + lane), from global (L2-hot)
    float eb[64];
    {
        const float* __restrict__ ebp =
            (const float*)g_Eb4 + ((size_t)bh * NS + wv * 64 + lane) * 64;
#pragma unroll
        for (int i = 0; i < 16; ++i) {
            const float4 v = *reinterpret_cast<const float4*>(ebp + i * 4);
            eb[i * 4 + 0] = v.x; eb[i * 4 + 1] = v.y;
            eb[i * 4 + 2] = v.z; eb[i * 4 + 3] = v.w;
        }
    }

    const float* __restrict__ ea =
        (const float*)g_Ea4 + ((size_t)bh * NT + t0) * 64; // wave-uniform

    // ---------------- Phase A: raw scores (12 rows, zero LDS) ----------------
    float p[12];
#pragma unroll
    for (int r = 0; r < 12; ++r) {
        const float* __restrict__ ear = ea + r * 64;
        float a0 = 0.f, a1 = 0.f, a2 = 0.f, a3 = 0.f;
#pragma unroll
        for (int e = 0; e < 64; e += 4) {
            a0 = fmaf(v_w[e + 0], __builtin_amdgcn_rcpf(fmaf(ear[e + 0], eb[e + 0], 1.f)), a0);
            a1 = fmaf(v_w[e + 1], __builtin_amdgcn_rcpf(fmaf(ear[e + 1], eb[e + 1], 1.f)), a1);
            a2 = fmaf(v_w[e + 2], __builtin_amdgcn_rcpf(fmaf(ear[e + 2], eb[e + 2], 1.f)), a2);
            a3 = fmaf(v_w[e + 3], __builtin_amdgcn_rcpf(fmaf(ear[e + 3], eb[e + 3], 1.f)), a3);
        }
        p[r] = C0 - 2.f * ((a0 + a1) + (a2 + a3));
    }

    // ---------------- Softmax (max-free; scores bounded ±24) ----------------
#pragma unroll
    for (int r = 0; r < 12; ++r) {
        p[r] = __builtin_amdgcn_exp2f(p[r] * LOG2E);
        float s = p[r];
#pragma unroll
        for (int o = 32; o > 0; o >>= 1) s += __shfl_xor(s, o, 64);
        if (lane == 0) ssum[r * 8 + wv] = s;
    }
    __syncthreads();

#pragma unroll
    for (int r = 0; r < 12; ++r) {
        const float tot = ((ssum[r * 8 + 0] + ssum[r * 8 + 1]) +
                           (ssum[r * 8 + 2] + ssum[r * 8 + 3])) +
                          (ssum[r * 8 + 4] + ssum[r * 8 + 5]);
        p[r] *= __builtin_amdgcn_rcpf(tot);
        Pl[r * 388 + wv * 64 + lane] = p[r];
        attn[((size_t)bh * NT + t0 + r) * NS + wv * 64 + lane] = p[r];
    }

    // ---------------- PV: out[r][d] = sum_s P[r][s] V[s][d] ----------------
    const int g  = lane >> 4;        // s-subgroup 0..3
    const int dq = (lane & 15) * 4;  // d-quad
    const int r0 = 2 * wv, r1 = 2 * wv + 1;
    float4 O0 = {0.f, 0.f, 0.f, 0.f};
    float4 O1 = {0.f, 0.f, 0.f, 0.f};
    const float4* __restrict__ Vg =
        reinterpret_cast<const float4*>(V + (size_t)bh * NS * 64);

    for (int sc = 0; sc < 6; ++sc) {
        __syncthreads(); // Pl written (sc==0) / previous chunk consumed
        for (int j = tid; j < 1024; j += 384) {
            const float4 v = Vg[sc * 1024 + j];
            const int row = j >> 4;
            const int c4  = j & 15;
            *reinterpret_cast<float4*>(&Vt[row * 68 + c4 * 4]) = v;
        }
        __syncthreads();

        const float* __restrict__ P0 = &Pl[r0 * 388 + sc * 64];
        const float* __restrict__ P1 = &Pl[r1 * 388 + sc * 64];
#pragma unroll
        for (int s4 = 0; s4 < 16; ++s4) {
            const int sl = s4 * 4 + g;
            const float4 v4 = *reinterpret_cast<const float4*>(&Vt[sl * 68 + dq]);
            const float q0 = P0[sl];
            const float q1 = P1[sl];
            O0.x = fmaf(q0, v4.x, O0.x); O0.y = fmaf(q0, v4.y, O0.y);
            O0.z = fmaf(q0, v4.z, O0.z); O0.w = fmaf(q0, v4.w, O0.w);
            O1.x = fmaf(q1, v4.x, O1.x); O1.y = fmaf(q1, v4.y, O1.y);
            O1.z = fmaf(q1, v4.z, O1.z); O1.w = fmaf(q1, v4.w, O1.w);
        }
    }

    // reduce across the 4 s-subgroups (lane bits 4,5)
#pragma unroll
    for (int o = 16; o <= 32; o <<= 1) {
        O0.x += __shfl_xor(O0.x, o, 64); O0.y += __shfl_xor(O0.y, o, 64);
        O0.z += __shfl_xor(O0.z, o, 64); O0.w += __shfl_xor(O0.w, o, 64);
        O1.x += __shfl_xor(O1.x, o, 64); O1.y += __shfl_xor(O1.y, o, 64);
        O1.z += __shfl_xor(O1.z, o, 64); O1.w += __shfl_xor(O1.w, o, 64);
    }
    if (g == 0) {
        float* __restrict__ op = out + ((size_t)bh * NT + t0 + r0) * 64 + dq;
        *reinterpret_cast<float4*>(op)      = O0;
        *reinterpret_cast<float4*>(op + 64) = O1;
    }
}

extern "C" void kernel_launch(void* const* d_in, const int* in_sizes, int n_in,
                              void* d_out, int out_size, void* d_ws, size_t ws_size,
                              hipStream_t stream) {
    const float* q  = (const float*)d_in[0];
    const float* k  = (const float*)d_in[1];
    const float* v  = (const float*)d_in[2];
    const float* Wq = (const float*)d_in[3];
    const float* Wk = (const float*)d_in[4];
    const float* vw = (const float*)d_in[5];

    float* out  = (float*)d_out;              // (b,h,t,d) = 393216
    float* attn = out + (size_t)BH * NT * DD; // (b,h,t,s) = 2359296

    k1_proj <<<384, 256, 0, stream>>>(q, k, Wq, Wk);
    k2_fused<<<512, 384, 0, stream>>>(vw, v, out, attn);
}